// Round 2
// baseline (1758.591 us; speedup 1.0000x reference)
//
#include <hip/hip_runtime.h>
#include <math.h>

#define SQ   2048
#define DH   64
#define NHD  16
#define QB   64      // q rows per block (4 waves x 16)
#define TK   64      // k rows per LDS tile
#define KST  72      // short (bf16) row stride for Ks/Vt  (144B, 16B aligned, breaks bank conflicts)
#define PST  68      // float row stride for Ps            (272B, 16B aligned)
#define MWD  66      // mask words per row (64 used + pad)

typedef float f32x4  __attribute__((ext_vector_type(4)));
typedef short s16x8  __attribute__((ext_vector_type(8)));   // 8 bf16 = 4 VGPR (MFMA A/B frag)
typedef short s16x4  __attribute__((ext_vector_type(4)));

__device__ __forceinline__ short f2bf(float f) {
    union { float f; unsigned u; } x; x.f = f;
    unsigned r = (x.u + 0x7FFFu + ((x.u >> 16) & 1u)) >> 16;  // RNE
    return (short)(unsigned short)r;
}

__global__ __launch_bounds__(256)
void attn_fused(const float* __restrict__ Qg, const float* __restrict__ Kg,
                const float* __restrict__ Vg, const unsigned int* __restrict__ Mg,
                float* __restrict__ Og, float* __restrict__ Pg)
{
    __shared__ __align__(16) unsigned int maskw[QB][MWD];  // 16896 B
    __shared__ __align__(16) short Ks[TK][KST];            //  9216 B
    __shared__ __align__(16) short Vt[DH][KST];            //  9216 B (V transposed, bf16)
    __shared__ __align__(16) float Ps[4][16][PST];         // 17408 B (per-wave P tile)

    const int tid  = threadIdx.x;
    const int lane = tid & 63;
    const int wv   = tid >> 6;        // wave 0..3
    const int lq   = lane & 15;       // A/B frag row/col ; C col
    const int lk   = lane >> 4;       // k-chunk group    ; C row group

    const int bh = blockIdx.y;        // 0..63
    const int b  = bh >> 4;           // / H
    const int q0 = blockIdx.x * QB;

    // ---- detect mask layout (int32 0/1 vs 1-byte bool); deterministic ----
    bool byteLayout = false;
    #pragma unroll
    for (int i = 0; i < 64; ++i) byteLayout = byteLayout || (Mg[i] > 1u);

    // ---- pack this block's mask slice into LDS bits via ballot ----
    if (!byteLayout) {
        const unsigned int* mrow = Mg + ((size_t)b * SQ + q0) * SQ;
        for (int r = wv; r < QB; r += 4) {
            const unsigned int* rp = mrow + (size_t)r * SQ;
            #pragma unroll 4
            for (int i = 0; i < 32; ++i) {
                unsigned int v = rp[i * 64 + lane];
                unsigned long long bits = __ballot(v != 0u);
                if (lane == 0) {
                    maskw[r][2 * i]     = (unsigned int)bits;
                    maskw[r][2 * i + 1] = (unsigned int)(bits >> 32);
                }
            }
        }
    } else {
        const unsigned char* mrow = (const unsigned char*)Mg + ((size_t)b * SQ + q0) * SQ;
        for (int r = wv; r < QB; r += 4) {
            const unsigned char* rp = mrow + (size_t)r * SQ;
            #pragma unroll 4
            for (int i = 0; i < 32; ++i) {
                unsigned char v = rp[i * 64 + lane];
                unsigned long long bits = __ballot(v != 0);
                if (lane == 0) {
                    maskw[r][2 * i]     = (unsigned int)bits;
                    maskw[r][2 * i + 1] = (unsigned int)(bits >> 32);
                }
            }
        }
    }

    // ---- load Q A-fragments (row = lane%16, k = 32c + 8*(lane/16) + j) ----
    s16x8 qf[2];
    {
        const float* qrow = Qg + ((size_t)bh * SQ + q0 + wv * 16 + lq) * DH;
        #pragma unroll
        for (int c = 0; c < 2; ++c) {
            const float4* p = (const float4*)(qrow + c * 32 + lk * 8);
            float4 a = p[0], bb = p[1];
            qf[c][0]=f2bf(a.x);  qf[c][1]=f2bf(a.y);  qf[c][2]=f2bf(a.z);  qf[c][3]=f2bf(a.w);
            qf[c][4]=f2bf(bb.x); qf[c][5]=f2bf(bb.y); qf[c][6]=f2bf(bb.z); qf[c][7]=f2bf(bb.w);
        }
    }
    __syncthreads();   // maskw ready

    // ================= sweep 1: online row max m and denom l =================
    float m[4], l[4];
    #pragma unroll
    for (int r = 0; r < 4; ++r) { m[r] = -3.3e38f; l[r] = 0.f; }

    for (int kt = 0; kt < SQ / TK; ++kt) {
        {   // stage K tile as bf16
            const float* ksrc = Kg + ((size_t)bh * SQ + kt * TK) * DH;
            #pragma unroll
            for (int ii = 0; ii < 4; ++ii) {
                int idx = tid + ii * 256;               // 0..1023 float4s
                int r = idx >> 4, d0 = (idx & 15) * 4;
                float4 v = *(const float4*)(ksrc + r * DH + d0);
                s16x4 s; s[0]=f2bf(v.x); s[1]=f2bf(v.y); s[2]=f2bf(v.z); s[3]=f2bf(v.w);
                *(s16x4*)&Ks[r][d0] = s;
            }
        }
        __syncthreads();
        #pragma unroll
        for (int nt = 0; nt < 4; ++nt) {
            f32x4 acc = {0.f, 0.f, 0.f, 0.f};
            s16x8 kf0 = *(const s16x8*)&Ks[nt * 16 + lq][lk * 8];
            s16x8 kf1 = *(const s16x8*)&Ks[nt * 16 + lq][32 + lk * 8];
            acc = __builtin_amdgcn_mfma_f32_16x16x32_bf16(qf[0], kf0, acc, 0, 0, 0);
            acc = __builtin_amdgcn_mfma_f32_16x16x32_bf16(qf[1], kf1, acc, 0, 0, 0);
            const int n0  = kt * TK + nt * 16;
            const int wrd = (n0 + lq) >> 5;
            const int bit = (n0 + lq) & 31;
            #pragma unroll
            for (int r = 0; r < 4; ++r) {
                const int rl = wv * 16 + lk * 4 + r;
                float w = acc[r] * 0.125f;
                if ((maskw[rl][wrd] >> bit) & 1u) w = -1e30f;
                float mn = fmaxf(m[r], w);
                l[r] = l[r] * __expf(m[r] - mn) + __expf(w - mn);
                m[r] = mn;
            }
        }
        __syncthreads();
    }

    // ---- reduce (m,l) across the 16 column-lanes of each row group ----
    float linv[4];
    #pragma unroll
    for (int r = 0; r < 4; ++r) {
        #pragma unroll
        for (int x = 1; x < 16; x <<= 1) {
            float mo = __shfl_xor(m[r], x, 64);
            float lo = __shfl_xor(l[r], x, 64);
            float mn = fmaxf(m[r], mo);
            l[r] = l[r] * __expf(m[r] - mn) + lo * __expf(mo - mn);
            m[r] = mn;
        }
        linv[r] = 1.0f / l[r];
    }

    // ================= sweep 2: P write + O = P.V =================
    f32x4 oa[4];
    #pragma unroll
    for (int dt = 0; dt < 4; ++dt) oa[dt] = (f32x4){0.f, 0.f, 0.f, 0.f};

    // direct per-lane P store base: row block for this wave
    float* Pdir = Pg + (size_t)bh * SQ * SQ + (size_t)(q0 + wv * 16) * SQ;

    for (int kt = 0; kt < SQ / TK; ++kt) {
        {   // stage K (bf16) and V transposed (bf16)
            const float* ksrc = Kg + ((size_t)bh * SQ + kt * TK) * DH;
            #pragma unroll
            for (int ii = 0; ii < 4; ++ii) {
                int idx = tid + ii * 256;
                int r = idx >> 4, d0 = (idx & 15) * 4;
                float4 v = *(const float4*)(ksrc + r * DH + d0);
                s16x4 s; s[0]=f2bf(v.x); s[1]=f2bf(v.y); s[2]=f2bf(v.z); s[3]=f2bf(v.w);
                *(s16x4*)&Ks[r][d0] = s;
            }
            const float* vsrc = Vg + ((size_t)bh * SQ + kt * TK) * DH;
            #pragma unroll
            for (int ii = 0; ii < 16; ++ii) {
                int idx = tid + ii * 256;               // 0..4095 scalars
                int r = idx >> 6, d = idx & 63;
                Vt[d][r] = f2bf(vsrc[r * DH + d]);      // coalesced read, transposed write
            }
        }
        __syncthreads();

        #pragma unroll
        for (int nt = 0; nt < 4; ++nt) {
            f32x4 acc = {0.f, 0.f, 0.f, 0.f};
            s16x8 kf0 = *(const s16x8*)&Ks[nt * 16 + lq][lk * 8];
            s16x8 kf1 = *(const s16x8*)&Ks[nt * 16 + lq][32 + lk * 8];
            acc = __builtin_amdgcn_mfma_f32_16x16x32_bf16(qf[0], kf0, acc, 0, 0, 0);
            acc = __builtin_amdgcn_mfma_f32_16x16x32_bf16(qf[1], kf1, acc, 0, 0, 0);
            const int n0  = kt * TK + nt * 16;
            const int wrd = (n0 + lq) >> 5;
            const int bit = (n0 + lq) & 31;
            #pragma unroll
            for (int r = 0; r < 4; ++r) {
                const int rl = wv * 16 + lk * 4 + r;
                float w = acc[r] * 0.125f;
                if ((maskw[rl][wrd] >> bit) & 1u) w = -1e30f;
                float p = __expf(w - m[r]) * linv[r];
                Ps[wv][lk * 4 + r][nt * 16 + lq] = p;
                // direct global store of the EXACT value PV consumes
                Pdir[(size_t)(lk * 4 + r) * SQ + n0 + lq] = p;
            }
        }

        // PV MFMAs: A = P chunk (from Ps), B = V chunk (from Vt)
        #pragma unroll
        for (int c = 0; c < 2; ++c) {
            const float4* pp = (const float4*)&Ps[wv][lq][c * 32 + lk * 8];
            float4 a0 = pp[0], a1 = pp[1];
            s16x8 pa;
            pa[0]=f2bf(a0.x); pa[1]=f2bf(a0.y); pa[2]=f2bf(a0.z); pa[3]=f2bf(a0.w);
            pa[4]=f2bf(a1.x); pa[5]=f2bf(a1.y); pa[6]=f2bf(a1.z); pa[7]=f2bf(a1.w);
            #pragma unroll
            for (int dt = 0; dt < 4; ++dt) {
                s16x8 vb = *(const s16x8*)&Vt[dt * 16 + lq][c * 32 + lk * 8];
                oa[dt] = __builtin_amdgcn_mfma_f32_16x16x32_bf16(pa, vb, oa[dt], 0, 0, 0);
            }
        }
        __syncthreads();
    }

    // ---- write O (C layout: row = lk*4+r, col = dt*16+lq) ----
    {
        float* orow = Og + ((size_t)bh * SQ + q0 + wv * 16) * DH;
        #pragma unroll
        for (int dt = 0; dt < 4; ++dt)
            #pragma unroll
            for (int r = 0; r < 4; ++r)
                orow[(size_t)(lk * 4 + r) * DH + dt * 16 + lq] = oa[dt][r];
    }
}

extern "C" void kernel_launch(void* const* d_in, const int* in_sizes, int n_in,
                              void* d_out, int out_size, void* d_ws, size_t ws_size,
                              hipStream_t stream) {
    const float*        Q = (const float*)d_in[0];
    const float*        K = (const float*)d_in[1];
    const float*        V = (const float*)d_in[2];
    const unsigned int* M = (const unsigned int*)d_in[3];

    float* out  = (float*)d_out;
    float* outO = out;                                       // [B,H,S,D]
    float* outP = out + (size_t)4 * NHD * SQ * DH;           // [B,H,S,S]

    dim3 grid(SQ / QB, 4 * NHD);
    dim3 block(256);
    hipLaunchKernelGGL(attn_fused, grid, block, 0, stream, Q, K, V, M, outO, outP);
}

// Round 3
// 522.280 us; speedup vs baseline: 3.3671x; 3.3671x over previous
//
#include <hip/hip_runtime.h>
#include <math.h>

#define SQ   2048
#define DH   64
#define NH   16
#define NB   4
#define QB   64      // q rows per block (4 waves x 16)
#define TK   64      // k rows per tile
#define MWD  68      // mask words per row (64 used + 4 pad; keeps rows 16B-aligned)
#define PST  68      // float row stride for Ps

typedef float f32x4  __attribute__((ext_vector_type(4)));
typedef short s16x8  __attribute__((ext_vector_type(8)));
typedef short s16x4  __attribute__((ext_vector_type(4)));

__device__ __forceinline__ short f2bf(float f) {
    union { float f; unsigned u; } x; x.f = f;
    unsigned r = (x.u + 0x7FFFu + ((x.u >> 16) & 1u)) >> 16;  // RNE
    return (short)(unsigned short)r;
}

__device__ __forceinline__ void gll16(const void* g, void* l) {
    __builtin_amdgcn_global_load_lds(
        (const __attribute__((address_space(1))) unsigned int*)g,
        (__attribute__((address_space(3))) unsigned int*)l, 16, 0, 0);
}

// ---------------- prepack 1: mask -> bitmask [B][S][64 words] ----------------
__global__ __launch_bounds__(64)
void mask_pack(const unsigned int* __restrict__ Mg, unsigned int* __restrict__ mb)
{
    const int row  = blockIdx.x;           // 0 .. NB*SQ-1
    const int lane = threadIdx.x;
    bool byteLayout = false;
    #pragma unroll
    for (int i = 0; i < 16; ++i) byteLayout = byteLayout || (Mg[i] > 1u);
    unsigned int* out = mb + (size_t)row * 64;
    if (!byteLayout) {
        const unsigned int* rp = Mg + (size_t)row * SQ;
        #pragma unroll 4
        for (int i = 0; i < 32; ++i) {
            unsigned long long bits = __ballot(rp[i * 64 + lane] != 0u);
            if (lane == 0) { out[2*i] = (unsigned)bits; out[2*i+1] = (unsigned)(bits >> 32); }
        }
    } else {
        const unsigned char* rp = (const unsigned char*)Mg + (size_t)row * SQ;
        #pragma unroll 4
        for (int i = 0; i < 32; ++i) {
            unsigned long long bits = __ballot(rp[i * 64 + lane] != 0);
            if (lane == 0) { out[2*i] = (unsigned)bits; out[2*i+1] = (unsigned)(bits >> 32); }
        }
    }
}

// ------- prepack 2: K,V f32 -> bf16, tiled 64x64, XOR-swizzled granules ------
// LDS-flat layout per tile (shorts): L = r*64 + G'*8 + j, where the element
// stored there is  X[r][(G' ^ (r&7))*8 + j]  (involution; hot kernel reads
// with the same XOR -> conflict-free ds_read_b128 after linear global_load_lds)
// K tiles: rows r = k-index.  V tiles: rows r = d-index (pre-transposed).
__global__ __launch_bounds__(256)
void kv_pack(const float* __restrict__ Kg, const float* __restrict__ Vg,
             short* __restrict__ Ktg, short* __restrict__ Vtg)
{
    __shared__ float Vf[64][68];
    const int tid = threadIdx.x;
    const int bh  = blockIdx.x >> 5;
    const int kt  = blockIdx.x & 31;
    const float* ksrc = Kg + ((size_t)bh * SQ + kt * TK) * DH;
    const float* vsrc = Vg + ((size_t)bh * SQ + kt * TK) * DH;
    short* kd = Ktg + (size_t)(bh * 32 + kt) * 4096;
    short* vd = Vtg + (size_t)(bh * 32 + kt) * 4096;

    #pragma unroll
    for (int ii = 0; ii < 4; ++ii) {
        int idx = tid + ii * 256;          // 0..1023 float4 slots
        int r = idx >> 4, c0 = (idx & 15) * 4;
        float4 kv = *(const float4*)(ksrc + r * DH + c0);
        s16x4 s; s[0]=f2bf(kv.x); s[1]=f2bf(kv.y); s[2]=f2bf(kv.z); s[3]=f2bf(kv.w);
        int gp = (c0 >> 3) ^ (r & 7);
        *(s16x4*)(kd + r * 64 + gp * 8 + (c0 & 7)) = s;
        float4 vv = *(const float4*)(vsrc + r * DH + c0);
        *(float4*)&Vf[r][c0] = vv;
    }
    __syncthreads();
    #pragma unroll
    for (int ii = 0; ii < 4; ++ii) {
        int idx = tid + ii * 256;
        int d = idx >> 4, k0 = (idx & 15) * 4;
        s16x4 s;
        s[0]=f2bf(Vf[k0+0][d]); s[1]=f2bf(Vf[k0+1][d]);
        s[2]=f2bf(Vf[k0+2][d]); s[3]=f2bf(Vf[k0+3][d]);
        int gp = (k0 >> 3) ^ (d & 7);
        *(s16x4*)(vd + d * 64 + gp * 8 + (k0 & 7)) = s;
    }
}

// ------------------------------- hot kernel ---------------------------------
__global__ __launch_bounds__(256)
void attn_fused(const float* __restrict__ Qg,
                const short* __restrict__ Ktg, const short* __restrict__ Vtg,
                const unsigned int* __restrict__ mb,
                float* __restrict__ Og, float* __restrict__ Pg)
{
    __shared__ __align__(16) unsigned int maskw[QB][MWD]; // 17408 B
    __shared__ __align__(16) short Ks[TK * 64];           //  8192 B (swizzled tile)
    __shared__ __align__(16) short Vt[TK * 64];           //  8192 B (swizzled tile)
    __shared__ __align__(16) float Ps[4][16][PST];        // 17408 B

    const int tid  = threadIdx.x;
    const int lane = tid & 63;
    const int wv   = tid >> 6;
    const int lq   = lane & 15;
    const int lk   = lane >> 4;

    const int bh = blockIdx.y;
    const int b  = bh >> 4;
    const int q0 = blockIdx.x * QB;

    // ---- load packed mask slice: 64 rows x 64 words, 4 uint4 per thread ----
    {
        const uint4* src = (const uint4*)(mb + ((size_t)b * SQ + q0) * 64);
        #pragma unroll
        for (int ii = 0; ii < 4; ++ii) {
            int fl = tid + ii * 256;            // uint4 index, 16 per row
            int r = fl >> 4, w = (fl & 15) * 4;
            uint4 v = src[fl];
            *(uint4*)&maskw[r][w] = v;
        }
    }

    // ---- Q A-fragments from f32 (row = lq, k = 32c + 8*lk + j) ----
    s16x8 qf[2];
    {
        const float* qrow = Qg + ((size_t)bh * SQ + q0 + wv * 16 + lq) * DH;
        #pragma unroll
        for (int c = 0; c < 2; ++c) {
            const float4* p = (const float4*)(qrow + c * 32 + lk * 8);
            float4 a = p[0], bb = p[1];
            qf[c][0]=f2bf(a.x);  qf[c][1]=f2bf(a.y);  qf[c][2]=f2bf(a.z);  qf[c][3]=f2bf(a.w);
            qf[c][4]=f2bf(bb.x); qf[c][5]=f2bf(bb.y); qf[c][6]=f2bf(bb.z); qf[c][7]=f2bf(bb.w);
        }
    }
    __syncthreads();

    const size_t ktb = (size_t)bh * 32;
    const int swz0 = (lk ^ (lq & 7)) << 3;        // kf0 granule offset (shorts)
    const int swz1 = ((4 + lk) ^ (lq & 7)) << 3;  // kf1

    // ================= sweep 1: row max m, denom l =================
    float m[4], l[4];
    #pragma unroll
    for (int r = 0; r < 4; ++r) { m[r] = -3.3e38f; l[r] = 0.f; }

    #pragma unroll 1
    for (int kt = 0; kt < SQ / TK; ++kt) {
        const short* ks = Ktg + (ktb + kt) * 4096 + wv * 512 + lane * 8;
        gll16(ks,        Ks + wv * 512);
        gll16(ks + 2048, Ks + 2048 + wv * 512);
        __syncthreads();

        f32x4 acc[4];
        #pragma unroll
        for (int nt = 0; nt < 4; ++nt) {
            acc[nt] = (f32x4){0.f, 0.f, 0.f, 0.f};
            const int R = nt * 16 + lq;
            s16x8 kf0 = *(const s16x8*)(Ks + R * 64 + swz0);
            s16x8 kf1 = *(const s16x8*)(Ks + R * 64 + swz1);
            acc[nt] = __builtin_amdgcn_mfma_f32_16x16x32_bf16(qf[0], kf0, acc[nt], 0, 0, 0);
            acc[nt] = __builtin_amdgcn_mfma_f32_16x16x32_bf16(qf[1], kf1, acc[nt], 0, 0, 0);
        }
        #pragma unroll
        for (int r = 0; r < 4; ++r) {
            const int rl = wv * 16 + lk * 4 + r;
            const unsigned mw0 = maskw[rl][kt * 2];
            const unsigned mw1 = maskw[rl][kt * 2 + 1];
            float w[4];
            #pragma unroll
            for (int nt = 0; nt < 4; ++nt) {
                float x = acc[nt][r] * 0.125f;
                unsigned bits = (nt < 2) ? mw0 : mw1;
                if ((bits >> ((nt * 16 + lq) & 31)) & 1u) x = -1e30f;
                w[nt] = x;
            }
            float tmax = fmaxf(fmaxf(w[0], w[1]), fmaxf(w[2], w[3]));
            float lt = __expf(w[0]-tmax) + __expf(w[1]-tmax) + __expf(w[2]-tmax) + __expf(w[3]-tmax);
            float mn = fmaxf(m[r], tmax);
            l[r] = l[r] * __expf(m[r] - mn) + lt * __expf(tmax - mn);
            m[r] = mn;
        }
        __syncthreads();
    }

    // ---- reduce (m,l) across the 16 column-lanes of each row group ----
    float linv[4];
    #pragma unroll
    for (int r = 0; r < 4; ++r) {
        #pragma unroll
        for (int x = 1; x < 16; x <<= 1) {
            float mo = __shfl_xor(m[r], x, 64);
            float lo = __shfl_xor(l[r], x, 64);
            float mn = fmaxf(m[r], mo);
            l[r] = l[r] * __expf(m[r] - mn) + lo * __expf(mo - mn);
            m[r] = mn;
        }
        linv[r] = 1.0f / l[r];
    }

    // ================= sweep 2: P write + O = P.V =================
    f32x4 oa[4];
    #pragma unroll
    for (int dt = 0; dt < 4; ++dt) oa[dt] = (f32x4){0.f, 0.f, 0.f, 0.f};

    #pragma unroll 1
    for (int kt = 0; kt < SQ / TK; ++kt) {
        const short* ks = Ktg + (ktb + kt) * 4096 + wv * 512 + lane * 8;
        const short* vs = Vtg + (ktb + kt) * 4096 + wv * 512 + lane * 8;
        gll16(ks,        Ks + wv * 512);
        gll16(ks + 2048, Ks + 2048 + wv * 512);
        gll16(vs,        Vt + wv * 512);
        gll16(vs + 2048, Vt + 2048 + wv * 512);
        __syncthreads();

        #pragma unroll
        for (int nt = 0; nt < 4; ++nt) {
            f32x4 acc = {0.f, 0.f, 0.f, 0.f};
            const int R = nt * 16 + lq;
            s16x8 kf0 = *(const s16x8*)(Ks + R * 64 + swz0);
            s16x8 kf1 = *(const s16x8*)(Ks + R * 64 + swz1);
            acc = __builtin_amdgcn_mfma_f32_16x16x32_bf16(qf[0], kf0, acc, 0, 0, 0);
            acc = __builtin_amdgcn_mfma_f32_16x16x32_bf16(qf[1], kf1, acc, 0, 0, 0);
            #pragma unroll
            for (int r = 0; r < 4; ++r) {
                const int rl = wv * 16 + lk * 4 + r;
                const unsigned bits = maskw[rl][kt * 2 + (nt >> 1)];
                float x = acc[r] * 0.125f;
                if ((bits >> ((nt * 16 + lq) & 31)) & 1u) x = -1e30f;
                float p = __expf(x - m[r]) * linv[r];
                Ps[wv][lk * 4 + r][nt * 16 + lq] = p;
            }
        }
        __syncthreads();   // Ps tile complete (cross-lane LDS ordering)

        // coalesced P write: 4 rows x 256B per inst
        float* Pw = Pg + (size_t)bh * SQ * SQ + (size_t)(q0 + wv * 16) * SQ + kt * TK;
        #pragma unroll
        for (int i = 0; i < 4; ++i) {
            int f = lane + i * 64;
            int row = f >> 4, c4 = f & 15;
            float4 pv = *(const float4*)&Ps[wv][row][c4 * 4];
            *(float4*)(Pw + (size_t)row * SQ + c4 * 4) = pv;
        }

        // PV MFMAs
        #pragma unroll
        for (int c = 0; c < 2; ++c) {
            const float4* pp = (const float4*)&Ps[wv][lq][c * 32 + lk * 8];
            float4 a0 = pp[0], a1 = pp[1];
            s16x8 pa;
            pa[0]=f2bf(a0.x); pa[1]=f2bf(a0.y); pa[2]=f2bf(a0.z); pa[3]=f2bf(a0.w);
            pa[4]=f2bf(a1.x); pa[5]=f2bf(a1.y); pa[6]=f2bf(a1.z); pa[7]=f2bf(a1.w);
            #pragma unroll
            for (int dt = 0; dt < 4; ++dt) {
                const int Rv = dt * 16 + lq;
                const int swzv = (((4 * c + lk) ^ (lq & 7)) << 3);
                s16x8 vb = *(const s16x8*)(Vt + Rv * 64 + swzv);
                oa[dt] = __builtin_amdgcn_mfma_f32_16x16x32_bf16(pa, vb, oa[dt], 0, 0, 0);
            }
        }
        __syncthreads();   // before next staging overwrites Ks/Vt
    }

    // ---- write O ----
    {
        float* orow = Og + ((size_t)bh * SQ + q0 + wv * 16) * DH;
        #pragma unroll
        for (int dt = 0; dt < 4; ++dt)
            #pragma unroll
            for (int r = 0; r < 4; ++r)
                orow[(size_t)(lk * 4 + r) * DH + dt * 16 + lq] = oa[dt][r];
    }
}

extern "C" void kernel_launch(void* const* d_in, const int* in_sizes, int n_in,
                              void* d_out, int out_size, void* d_ws, size_t ws_size,
                              hipStream_t stream) {
    const float*        Q = (const float*)d_in[0];
    const float*        K = (const float*)d_in[1];
    const float*        V = (const float*)d_in[2];
    const unsigned int* M = (const unsigned int*)d_in[3];

    float* out  = (float*)d_out;
    float* outO = out;                                    // [B,H,S,D]
    float* outP = out + (size_t)NB * NH * SQ * DH;        // [B,H,S,S]

    // workspace layout: mask bits (2 MB) | K tiled bf16 (16.8 MB) | V tiled (16.8 MB)
    unsigned int* mbits = (unsigned int*)d_ws;
    short* Ktg = (short*)(mbits + (size_t)NB * SQ * 64);
    short* Vtg = Ktg + (size_t)NB * NH * SQ * DH;

    hipLaunchKernelGGL(mask_pack, dim3(NB * SQ), dim3(64), 0, stream, M, mbits);
    hipLaunchKernelGGL(kv_pack, dim3(NB * NH * 32), dim3(256), 0, stream, K, V, Ktg, Vtg);
    hipLaunchKernelGGL(attn_fused, dim3(SQ / QB, NB * NH), dim3(256), 0, stream,
                       Q, Ktg, Vtg, mbits, outO, outP);
}